// Round 1
// baseline (283.244 us; speedup 1.0000x reference)
//
#include <hip/hip_runtime.h>

namespace {

constexpr int NXc = 200, NYc = 200;
constexpr int NCELL = NXc * NYc;
constexpr int TSTEPS = 300;          // scan length
constexpr int SRC_I = 30, SRC_J = 100;
constexpr int PNc = 20;              // PML_N
constexpr float Hc = 1.005f;         // DT*2.01

// ---- temporal blocking config ----
constexpr int T_SUB = 24;            // substeps per launch (halo width)
constexpr int LT    = 64;            // loaded tile edge (rows & cols)
constexpr int VT    = LT - 2 * T_SUB;          // 16 valid
constexpr int TI    = (NXc + VT - 1) / VT;     // 13 tiles in i
constexpr int TJ    = (NYc + VT - 1) / VT;     // 13 tiles in j
constexpr int NSTEP_TOT = TSTEPS - 1;          // 299 updates after initial impulse
constexpr int NLAUNCH   = (NSTEP_TOT + T_SUB - 1) / T_SUB; // 13
constexpr int GSTRIDE = 304;         // g[p] row stride (>=300)

// ---- probe owner constants (compile-time) ----
constexpr int PROBE_I = 170;
constexpr int PTX = PROBE_I / VT;                      // owning tile row
constexpr int PRr = PROBE_I - (PTX * VT - T_SUB);      // local row in tile
static_assert(PRr >= T_SUB && PRr < T_SUB + VT, "probe row must be in valid interior");
constexpr int PW  = PRr >> 4;                          // owning wave
constexpr int PCc = PRr & 15;                          // register index within run

constexpr int PJ0 = 50, PJ1 = 100, PJ2 = 150;
constexpr int PTY0 = PJ0 / VT; constexpr int PCOL0 = PJ0 - (PTY0 * VT - T_SUB);
constexpr int PTY1 = PJ1 / VT; constexpr int PCOL1 = PJ1 - (PTY1 * VT - T_SUB);
constexpr int PTY2 = PJ2 / VT; constexpr int PCOL2 = PJ2 - (PTY2 * VT - T_SUB);
static_assert(PCOL0 >= T_SUB && PCOL0 < T_SUB + VT, "");
static_assert(PCOL1 >= T_SUB && PCOL1 < T_SUB + VT, "");
static_assert(PCOL2 >= T_SUB && PCOL2 < T_SUB + VT, "");
constexpr int PTID0 = (PW << 6) | PCOL0;
constexpr int PTID1 = (PW << 6) | PCOL1;
constexpr int PTID2 = (PW << 6) | PCOL2;

} // namespace

// ---------------------------------------------------------------------------
// Setup: compute P,Q,R coefficient fields from rho, init impulse state, g[p][0]=0
//   y = A*(8*y1 - Bm*y2 + c2*lap(y1)),  A=1/(4+b), Bm=4-b, lap=(nsum-4u)/H^2
//   =>  y = P*y1 - Q*y2 + R*nsum
//   P = A*(8 - 4*c2/H^2), Q = A*(4-b), R = A*c2/H^2
// ---------------------------------------------------------------------------
__global__ __launch_bounds__(256) void setup_kernel(
    const float* __restrict__ rho,
    float* __restrict__ Pf, float* __restrict__ Qf, float* __restrict__ Rf,
    float* __restrict__ y1, float* __restrict__ y2, float* __restrict__ g)
{
    int idx = blockIdx.x * 256 + threadIdx.x;
    if (idx >= NCELL) return;
    int i = idx / NYc, j = idx % NYc;

    // lpf(rho): 0.5*r + 0.125*(n+s+e+w), zero padded
    float r  = rho[idx];
    float rn = (i > 0)       ? rho[idx - NYc] : 0.f;
    float rs = (i < NXc - 1) ? rho[idx + NYc] : 0.f;
    float rw = (j > 0)       ? rho[idx - 1]   : 0.f;
    float re = (j < NYc - 1) ? rho[idx + 1]   : 0.f;
    float l  = 0.5f * r + 0.125f * (rn + rs + rw + re);

    float t_eta = tanhf(100.f * 0.5f);              // = 1.0f
    float denom = t_eta + tanhf(100.f * (1.f - 0.5f));
    float rho_p = (t_eta + tanhf(100.f * (l - 0.5f))) / denom;
    float c  = 1.0f + (0.9f - 1.0f) * rho_p;
    float c2 = c * c;

    // PML damping b
    float ui = 0.f, uj = 0.f;
    if (i <= PNc) ui = (float)(PNc - i) * 0.05f;
    else if (i >= NXc - PNc - 1) ui = (float)(i - (NXc - PNc - 1)) * 0.05f;
    if (j <= PNc) uj = (float)(PNc - j) * 0.05f;
    else if (j >= NYc - PNc - 1) uj = (float)(j - (NYc - PNc - 1)) * 0.05f;
    float ui2 = ui * ui, uj2 = uj * uj;
    float bx = 3.0f * ui2 * ui2;
    float by = 3.0f * uj2 * uj2;
    float b  = sqrtf(bx * bx + by * by);

    float A = 1.0f / (4.0f + b);
    float h2inv = 1.0f / (Hc * Hc);
    Pf[idx] = A * (8.0f - 4.0f * c2 * h2inv);
    Qf[idx] = A * (4.0f - b);
    Rf[idx] = A * c2 * h2inv;

    // impulse initial condition: y_0 = delta at source, y_{-1} = 0
    y1[idx] = (idx == SRC_I * NYc + SRC_J) ? 1.0f : 0.f;
    y2[idx] = 0.f;
    if (idx < 3) g[idx * GSTRIDE + 0] = 0.f;   // g[p][0] = 0 (source not at probe)
}

// ---------------------------------------------------------------------------
// Temporal-blocked stepper: each block loads a 64x64 tile (valid 16x16 interior,
// halo 24) into registers, advances ns (<=24) steps, records probes, writes back
// the valid interior. Thread layout: lane = col (64 wide), wave w owns rows
// 16w..16w+15 in registers. N/S run boundaries via tiny LDS arrays, E/W via shfl.
// Out-of-domain cells have P=Q=R=0 -> stay exactly 0 (zero-padding semantics).
// ---------------------------------------------------------------------------
__global__ __launch_bounds__(256, 1) void step_kernel(
    const float* __restrict__ Pf, const float* __restrict__ Qf, const float* __restrict__ Rf,
    const float* __restrict__ y1in, const float* __restrict__ y2in,
    float* __restrict__ y1out, float* __restrict__ y2out,
    float* __restrict__ g, int s0, int ns)
{
    const int ty = blockIdx.x;   // tile index along j (cols)
    const int tx = blockIdx.y;   // tile index along i (rows)
    const int tid = threadIdx.x;
    const int lane = tid & 63;   // local col
    const int w = tid >> 6;      // wave: vertical run 16w..16w+15

    const int i0 = tx * VT - T_SUB;   // global i of local row 0
    const int j0 = ty * VT - T_SUB;   // global j of local col 0
    const int gj = j0 + lane;
    const bool jin = (gj >= 0) && (gj < NYc);

    float y1r[16], y2r[16], Pr[16], Qr[16], Rr[16];
    #pragma unroll
    for (int c = 0; c < 16; ++c) {
        int gi = i0 + (w << 4) + c;
        bool in = jin && (gi >= 0) && (gi < NXc);
        int gidx = gi * NYc + gj;
        y1r[c] = in ? y1in[gidx] : 0.f;
        y2r[c] = in ? y2in[gidx] : 0.f;
        Pr[c]  = in ? Pf[gidx]   : 0.f;
        Qr[c]  = in ? Qf[gidx]   : 0.f;
        Rr[c]  = in ? Rf[gidx]   : 0.f;
    }

    __shared__ float topSh[4][64];   // wave w's row 0
    __shared__ float botSh[4][64];   // wave w's row 15

    for (int k = 0; k < ns; ++k) {
        topSh[w][lane] = y1r[0];
        botSh[w][lane] = y1r[15];
        __syncthreads();
        float nTop = (w > 0) ? botSh[w - 1][lane] : 0.f;  // tile edge: invalid region
        float sBot = (w < 3) ? topSh[w + 1][lane] : 0.f;
        __syncthreads();  // reads done before next iteration's writes

        float yn[16];
        #pragma unroll
        for (int c = 0; c < 16; ++c) {
            float nv = (c == 0)  ? nTop : y1r[c - 1];
            float sv = (c == 15) ? sBot : y1r[c + 1];
            float ev = __shfl_down(y1r[c], 1, 64);   // col+1
            float wv = __shfl_up  (y1r[c], 1, 64);   // col-1
            yn[c] = Pr[c] * y1r[c] - Qr[c] * y2r[c] + Rr[c] * ((nv + sv) + (ev + wv));
        }
        #pragma unroll
        for (int c = 0; c < 16; ++c) { y2r[c] = y1r[c]; y1r[c] = yn[c]; }

        // record probes g[p][t], t = s0+k+1 (probe cells always in valid interior)
        if (tx == PTX) {
            int t = s0 + k + 1;
            if (ty == PTY0 && tid == PTID0) g[0 * GSTRIDE + t] = y1r[PCc];
            if (ty == PTY1 && tid == PTID1) g[1 * GSTRIDE + t] = y1r[PCc];
            if (ty == PTY2 && tid == PTID2) g[2 * GSTRIDE + t] = y1r[PCc];
        }
    }

    // write back valid interior [T_SUB, T_SUB+VT) clipped to domain
    #pragma unroll
    for (int c = 0; c < 16; ++c) {
        int r = (w << 4) + c;
        int gi = i0 + r;
        if (r >= T_SUB && r < T_SUB + VT &&
            lane >= T_SUB && lane < T_SUB + VT &&
            gi < NXc && gj < NYc && gi >= 0 && gj >= 0) {
            int gidx = gi * NYc + gj;
            y1out[gidx] = y1r[c];
            y2out[gidx] = y2r[c];
        }
    }
}

// ---------------------------------------------------------------------------
// Convolution + intensity + normalize: one block per batch element.
// probes_t = sum_s x[s]*g[p][t-s];  I_p = sum_t probes_t^2;  out = I/sum_p I
// ---------------------------------------------------------------------------
__global__ __launch_bounds__(256) void conv_kernel(
    const float* __restrict__ x, const float* __restrict__ g, float* __restrict__ out)
{
    const int b = blockIdx.x;
    __shared__ float xs[304];
    __shared__ float gsm[3][304];
    __shared__ float red[3][4];

    for (int idx = threadIdx.x; idx < TSTEPS; idx += 256) {
        xs[idx] = x[b * TSTEPS + idx];
        gsm[0][idx] = g[0 * GSTRIDE + idx];
        gsm[1][idx] = g[1 * GSTRIDE + idx];
        gsm[2][idx] = g[2 * GSTRIDE + idx];
    }
    __syncthreads();

    float acc0 = 0.f, acc1 = 0.f, acc2 = 0.f;
    for (int t = threadIdx.x; t < TSTEPS; t += 256) {
        float c0 = 0.f, c1 = 0.f, c2 = 0.f;
        for (int s = 0; s <= t; ++s) {
            float xv = xs[s];
            c0 += xv * gsm[0][t - s];
            c1 += xv * gsm[1][t - s];
            c2 += xv * gsm[2][t - s];
        }
        acc0 += c0 * c0; acc1 += c1 * c1; acc2 += c2 * c2;
    }

    // block reduction (4 waves)
    float accs[3] = {acc0, acc1, acc2};
    #pragma unroll
    for (int p = 0; p < 3; ++p) {
        float v = accs[p];
        #pragma unroll
        for (int off = 32; off > 0; off >>= 1) v += __shfl_down(v, off, 64);
        if ((threadIdx.x & 63) == 0) red[p][threadIdx.x >> 6] = v;
    }
    __syncthreads();
    if (threadIdx.x == 0) {
        float I0 = red[0][0] + red[0][1] + red[0][2] + red[0][3];
        float I1 = red[1][0] + red[1][1] + red[1][2] + red[1][3];
        float I2 = red[2][0] + red[2][1] + red[2][2] + red[2][3];
        float inv = 1.0f / (I0 + I1 + I2);
        out[b * 3 + 0] = I0 * inv;
        out[b * 3 + 1] = I1 * inv;
        out[b * 3 + 2] = I2 * inv;
    }
}

// ---------------------------------------------------------------------------
extern "C" void kernel_launch(void* const* d_in, const int* in_sizes, int n_in,
                              void* d_out, int out_size, void* d_ws, size_t ws_size,
                              hipStream_t stream)
{
    const float* x   = (const float*)d_in[0];   // (8, 300)
    const float* rho = (const float*)d_in[1];   // (200, 200)
    float* out = (float*)d_out;                 // (8, 3) float32

    float* base = (float*)d_ws;
    float* Pf = base;
    float* Qf = Pf + NCELL;
    float* Rf = Qf + NCELL;
    float* ya = Rf + NCELL;
    float* yb = ya + NCELL;
    float* yc = yb + NCELL;
    float* yd = yc + NCELL;
    float* g  = yd + NCELL;    // 3 * GSTRIDE floats

    setup_kernel<<<(NCELL + 255) / 256, 256, 0, stream>>>(rho, Pf, Qf, Rf, ya, yb, g);

    float* y1i = ya; float* y2i = yb; float* y1o = yc; float* y2o = yd;
    int s = 0;
    for (int l = 0; l < NLAUNCH; ++l) {
        int ns = NSTEP_TOT - s; if (ns > T_SUB) ns = T_SUB;
        step_kernel<<<dim3(TJ, TI), 256, 0, stream>>>(Pf, Qf, Rf, y1i, y2i, y1o, y2o, g, s, ns);
        float* t1 = y1i; y1i = y1o; y1o = t1;
        float* t2 = y2i; y2i = y2o; y2o = t2;
        s += ns;
    }

    conv_kernel<<<8, 256, 0, stream>>>(x, g, out);
}